// Round 8
// baseline (280.487 us; speedup 1.0000x reference)
//
#include <hip/hip_runtime.h>

#define NA 100000
#define NE 300000
#define STEPS 4
#define NTILES (NE / 16)        // 18750 (exact)
#define ATILES (NA / 16)        // 6250  (exact)

typedef _Float16 f16;
typedef _Float16 half8 __attribute__((ext_vector_type(8)));
using f32x4  = __attribute__((ext_vector_type(4))) float;
using short8 = __attribute__((ext_vector_type(8))) short;

// ---------------------------------------------------------------------------
// custom zero-fill (the rocclr fillBuffer kernel runs at 315 GB/s; this one
// streams float4 at full write BW)
// ---------------------------------------------------------------------------
__global__ __launch_bounds__(256) void zero_kernel(float4* __restrict__ p, int n4)
{
    int t = blockIdx.x * 256 + threadIdx.x;
    if (t < n4) p[t] = make_float4(0.f, 0.f, 0.f, 0.f);
}

// ---------------------------------------------------------------------------
// fp32 -> fp16 bulk converts: h (step-0) and bond (once)
// ---------------------------------------------------------------------------
__global__ __launch_bounds__(256) void conv_kernel(
    const float* __restrict__ src, f16* __restrict__ dst, int n8)
{
    int t = blockIdx.x * 256 + threadIdx.x;   // one half8 (8 elems) per thread
    if (t >= n8) return;
    float4 a = reinterpret_cast<const float4*>(src)[2 * t];
    float4 b = reinterpret_cast<const float4*>(src)[2 * t + 1];
    half8 o;
    o[0]=(f16)a.x; o[1]=(f16)a.y; o[2]=(f16)a.z; o[3]=(f16)a.w;
    o[4]=(f16)b.x; o[5]=(f16)b.y; o[6]=(f16)b.z; o[7]=(f16)b.w;
    reinterpret_cast<half8*>(dst)[t] = o;
}

// ---------------------------------------------------------------------------
// Preconvert weights to fp16: Wbt[k][i][j] pitch 32 (k=16 is bias matrix),
// Wihb / Whhb = [96][32] row-major.
// ---------------------------------------------------------------------------
__global__ __launch_bounds__(256) void prep_kernel(
    const float* __restrict__ Wb, const float* __restrict__ bb,
    const float* __restrict__ Wih, const float* __restrict__ Whh,
    f16* __restrict__ Wbt, f16* __restrict__ Wihb, f16* __restrict__ Whhb)
{
    int t = blockIdx.x * 256 + threadIdx.x;     // < 17*32*32 + 2*96*32 = 23552
    if (t < 17 * 32 * 32) {
        int j = t & 31, i = (t >> 5) & 31, k = t >> 10;
        float v = (k < 16) ? Wb[k * 1024 + i * 32 + j] : bb[i * 32 + j];
        Wbt[t] = (f16)v;                        // contiguous [k][i][j]
    } else if (t < 17 * 32 * 32 + 3072) {
        int u = t - 17 * 32 * 32;
        Wihb[u] = (f16)Wih[u];
    } else if (t < 17 * 32 * 32 + 6144) {
        int u = t - 17 * 32 * 32 - 3072;
        Whhb[u] = (f16)Whh[u];
    }
}

// ---------------------------------------------------------------------------
// msg: no LDS, 1 tile (16 edges) per wave. B-fragments read from global
// (34 KB, L1/L2-resident); c packed as 2x half8; dst read directly from pair
// (no shfl). Slim register budget -> 8 waves/SIMD.
// ---------------------------------------------------------------------------
__global__ __launch_bounds__(256, 8) void msg_kernel(
    const f16* __restrict__ hb,              // [NA][32] fp16
    const f16* __restrict__ bondh,           // [NE][16] fp16
    const int* __restrict__ pair,            // [NE][2] (dst, nbr)
    const f16* __restrict__ Wbt,             // [17][32][32] fp16
    float* __restrict__ agg)                 // [NA][32] fp32, pre-zeroed
{
    int wave = threadIdx.x >> 6;
    int lane = threadIdx.x & 63;
    int tile = blockIdx.x * 4 + wave;
    if (tile >= NTILES) return;

    int col  = lane & 15;        // A-row select / D-col (i)
    int kg   = lane >> 4;        // k-group: j = kg*8..kg*8+7
    int row0 = kg * 4;           // D rows held by this lane

    int base = tile * 16;
    int e    = base + col;

    int nbr = pair[2 * e + 1];
    half8 hf = *reinterpret_cast<const half8*>(hb + (size_t)nbr * 32 + kg * 8);

    half8 cA = *reinterpret_cast<const half8*>(bondh + (size_t)e * 16);
    half8 cB = *reinterpret_cast<const half8*>(bondh + (size_t)e * 16 + 8);

    f32x4 acc0 = {0.f, 0.f, 0.f, 0.f};
    f32x4 acc1 = {0.f, 0.f, 0.f, 0.f};

#pragma unroll
    for (int s = 0; s < 16; ++s) {
        half8 b0 = *reinterpret_cast<const half8*>(Wbt + (s * 32 + col) * 32 + kg * 8);
        half8 b1 = *reinterpret_cast<const half8*>(Wbt + (s * 32 + 16 + col) * 32 + kg * 8);
        f16 ch = (s < 8) ? cA[s] : cB[s - 8];
        half8 a = hf * ch;                     // v_pk_mul_f16 x4
        acc0 = __builtin_amdgcn_mfma_f32_16x16x32_f16(a, b0, acc0, 0, 0, 0);
        acc1 = __builtin_amdgcn_mfma_f32_16x16x32_f16(a, b1, acc1, 0, 0, 0);
    }
    {   // bias matrix (k=16): unscaled h
        half8 b0 = *reinterpret_cast<const half8*>(Wbt + (16 * 32 + col) * 32 + kg * 8);
        half8 b1 = *reinterpret_cast<const half8*>(Wbt + (16 * 32 + 16 + col) * 32 + kg * 8);
        acc0 = __builtin_amdgcn_mfma_f32_16x16x32_f16(hf, b0, acc0, 0, 0, 0);
        acc1 = __builtin_amdgcn_mfma_f32_16x16x32_f16(hf, b1, acc1, 0, 0, 0);
    }

#pragma unroll
    for (int r = 0; r < 4; ++r) {
        int dr = pair[2 * (base + row0 + r)];  // L1-hot (just read by this wave)
        atomicAdd(&agg[(size_t)dr * 32 + col],      acc0[r]);
        atomicAdd(&agg[(size_t)dr * 32 + 16 + col], acc1[r]);
    }
}

// ---------------------------------------------------------------------------
// GRU via MFMA (fp16). Consumes agg and ZEROES it in place (each 32B chunk
// read/written by exactly one lane) so the next step needs no memset.
// fp32 hout written only at the final step.
// ---------------------------------------------------------------------------
__global__ __launch_bounds__(256) void gru_kernel(
    float* __restrict__ agg,                  // [NA][32] fp32; zeroed on exit
    const f16* __restrict__ hb,               // [NA][32] fp16 (h_prev; rewritten)
    const f16* __restrict__ Wihb,             // [96][32] fp16
    const f16* __restrict__ Whhb,             // [96][32] fp16
    const float* __restrict__ bih, const float* __restrict__ bhh,
    float* __restrict__ hout, f16* __restrict__ hbf, int write_f32)
{
    int wave = threadIdx.x >> 6;
    int lane = threadIdx.x & 63;
    int tile = blockIdx.x * 4 + wave;
    if (tile >= ATILES) return;

    int base = tile * 16;
    int col  = lane & 15;
    int kg   = lane >> 4;

    half8 xfrag;
    {
        float4* x4 = reinterpret_cast<float4*>(agg + (size_t)(base + col) * 32 + kg * 8);
        float4 a = x4[0], b = x4[1];
        xfrag[0] = (f16)a.x; xfrag[1] = (f16)a.y; xfrag[2] = (f16)a.z; xfrag[3] = (f16)a.w;
        xfrag[4] = (f16)b.x; xfrag[5] = (f16)b.y; xfrag[6] = (f16)b.z; xfrag[7] = (f16)b.w;
        float4 zz = make_float4(0.f, 0.f, 0.f, 0.f);
        x4[0] = zz; x4[1] = zz;                // pre-zero agg for next step
    }
    half8 hfrag = *reinterpret_cast<const half8*>(hb + (size_t)(base + col) * 32 + kg * 8);

    f32x4 gi[6], gh[6];
#pragma unroll
    for (int t = 0; t < 6; ++t) {
        half8 bi = *reinterpret_cast<const half8*>(Wihb + (size_t)(t * 16 + col) * 32 + kg * 8);
        half8 bh = *reinterpret_cast<const half8*>(Whhb + (size_t)(t * 16 + col) * 32 + kg * 8);
        f32x4 z = {0.f, 0.f, 0.f, 0.f};
        gi[t] = __builtin_amdgcn_mfma_f32_16x16x32_f16(xfrag, bi, z, 0, 0, 0);
        gh[t] = __builtin_amdgcn_mfma_f32_16x16x32_f16(hfrag, bh, z, 0, 0, 0);
    }

#pragma unroll
    for (int hh = 0; hh < 2; ++hh) {
        int i  = hh * 16 + col;
        float br  = bih[i]      + bhh[i];
        float bz  = bih[32 + i] + bhh[32 + i];
        float bin = bih[64 + i];
        float bhn = bhh[64 + i];
#pragma unroll
        for (int reg = 0; reg < 4; ++reg) {
            int a = base + kg * 4 + reg;
            float r = 1.f / (1.f + __expf(-(gi[hh][reg] + gh[hh][reg] + br)));
            float z = 1.f / (1.f + __expf(-(gi[2 + hh][reg] + gh[2 + hh][reg] + bz)));
            float n = tanhf(gi[4 + hh][reg] + bin + r * (gh[4 + hh][reg] + bhn));
            float hp = (float)hb[(size_t)a * 32 + i];   // fp16 h_prev
            float o  = (1.f - z) * n + z * hp;
            if (write_f32) hout[(size_t)a * 32 + i] = o;
            hbf[(size_t)a * 32 + i] = (f16)o;
        }
    }
}

extern "C" void kernel_launch(void* const* d_in, const int* in_sizes, int n_in,
                              void* d_out, int out_size, void* d_ws, size_t ws_size,
                              hipStream_t stream)
{
    const float* atom = (const float*)d_in[0];
    const float* bond = (const float*)d_in[1];
    const int*   pair = (const int*)  d_in[2];
    const float* Wb   = (const float*)d_in[3];
    const float* bb   = (const float*)d_in[4];
    const float* W_ih = (const float*)d_in[5];
    const float* W_hh = (const float*)d_in[6];
    const float* b_ih = (const float*)d_in[7];
    const float* b_hh = (const float*)d_in[8];
    float* out = (float*)d_out;

    const size_t HB = (size_t)NA * 32 * sizeof(float);      // 12.8 MB
    float* agg   = (float*)d_ws;
    f16*   hbf   = (f16*)((char*)d_ws + HB);                // 6.4 MB
    f16*   bondh = (f16*)((char*)d_ws + HB + HB / 2);       // 9.6 MB
    f16*   Wbt   = bondh + (size_t)NE * 16;                 // 34.8 KB
    f16*   Wihb  = Wbt + 17 * 32 * 32;
    f16*   Whhb  = Wihb + 96 * 32;

    const int zero_blocks = (NA * 32 / 4 + 255) / 256;
    const int convh_blocks = (NA * 32 / 8 + 255) / 256;
    const int convb_blocks = (NE * 16 / 8 + 255) / 256;
    const int prep_blocks = (17 * 32 * 32 + 6144 + 255) / 256;
    const int msg_blocks  = (NTILES + 3) / 4;
    const int gru_blocks  = (ATILES + 3) / 4;

    zero_kernel<<<zero_blocks, 256, 0, stream>>>((float4*)agg, NA * 32 / 4);
    prep_kernel<<<prep_blocks, 256, 0, stream>>>(Wb, bb, W_ih, W_hh, Wbt, Wihb, Whhb);
    conv_kernel<<<convh_blocks, 256, 0, stream>>>(atom, hbf, NA * 32 / 8);
    conv_kernel<<<convb_blocks, 256, 0, stream>>>(bond, bondh, NE * 16 / 8);

    for (int s = 0; s < STEPS; ++s) {
        msg_kernel<<<msg_blocks, 256, 0, stream>>>(hbf, bondh, pair, Wbt, agg);
        gru_kernel<<<gru_blocks, 256, 0, stream>>>(agg, hbf, Wihb, Whhb,
                                                   b_ih, b_hh, out, hbf,
                                                   (s == STEPS - 1) ? 1 : 0);
    }
}